// Round 9
// baseline (4252.936 us; speedup 1.0000x reference)
//
#include <hip/hip_runtime.h>

// Shapes: VOCAB=128, EMBED=512, HIDDEN=1024, B=64, T=512. Inputs fp32, x int32.
// ws layout (bytes):
//   tableV : [128 vocab][4096 C] fp16   @ 0         (1 MB)  xin0+bias
//   fcwT   : [1024 k][128 v] fp16       @ 1048576   (256 KB)
//   bar    : [512 words] u32            @ 1310720   (2 KB)  flat barrier
//   hseq   : [514 buf][64 b][2048 k]f16 @ 1376256   (128.5 MB) fresh h per step
//
// Structure = R8 (best: 3712 us), ONE change this round:
//
// ASM-FORCED 16-DEEP A-LOADS (R9): R7 (sched_barrier) and R8 both left
// VGPR_Count at 84/128 -> regalloc never kept A0[8]+A1[8] (64 VGPR) live;
// the 16 A-loads issue in small windows = 4-8 serialized L2/L3/HBM
// latencies (~2-4 us/step, the unexplained bulk of R6's ~7 us chain).
// Fix: ONE asm volatile block issues all 16 global_load_dwordx4 into 16
// early-clobber "=&v" v8h outputs + a single s_waitcnt vmcnt(0). Regalloc
// MUST allocate 64 result VGPRs -> all 16 loads in flight, one latency.
// We run 1 block/CU (256 blocks/256 CUs), so VGPR up to 256 is free —
// but __launch_bounds__ must become (512,1): (512,2) would cap VGPR at
// 128 and spill. Expect VGPR ~190-240.
//
// A-LOAD DEDUP / LAYER-FUSED WAVES (R8): 8 waves/block; wave w loads hcat
// k-chunk w*256 ONCE; waves 0-3 keep two B-sets (w_hh0+w_ih1), emit L0
// tiles (zs slots 0-3) AND L1-xin1 tiles (slots 4-7); waves 4-7 keep
// w_hh1 (slots 8-11). Owner reduction: L0 = slots 0-3, L1 = slots 4-11.
// FRESH-BUFFER h EXCHANGE (R1): step it reads buffer it, writes buffer
// it+1; consumer XCD never touched buffer it+1 before step it+1 -> plain
// cached dwordx4 loads are coherent. Stores agent-scope relaxed atomics +
// vmcnt(0) before arrival. Line-ownership: cg = (blk&7)*16+t.
// buffer[t+2][b][1024+u] IS h2[t] -> FC reads hseq directly.
// FLAT m-SPLIT BARRIER (R2): two independent single-stage barriers, arrival
// adds spread over 8 words, tid0 polls min-of-8. (R5 lesson: never increase
// same-address atomic fan-in or poller count.)
// SWIZZLED LDS REDUCTION (R4): zs[slot12][r4][rq8][col32], col32 =
// (cb*16+colp)^((rq&1)<<4), colp=j*4+g; 2-way max write conflicts, b128
// owner reads (conflicts 2.0e8 -> 2.5e7 measured). __expf + division only.

typedef _Float16 v8h __attribute__((ext_vector_type(8)));
typedef float v4f __attribute__((ext_vector_type(4)));
typedef _Float16 h2v __attribute__((ext_vector_type(2)));
typedef unsigned long long u64t;

__device__ __forceinline__ float sigf(float x) {
  return 1.0f / (1.0f + __expf(-x));
}
__device__ __forceinline__ float tanhfast(float x) {
  // tanh = 1 - 2/(e^{2x}+1); graceful at +-inf (__expf -> inf/0)
  return 1.0f - 2.0f / (1.0f + __expf(2.0f * x));
}

// ---------------------------------------------------------------- prep ----
__global__ __launch_bounds__(256) void prep_kernel(
    const float* __restrict__ emb, const float* __restrict__ w_ih0,
    const float* __restrict__ b_ih0, const float* __restrict__ b_hh0,
    const float* __restrict__ fc_w, _Float16* __restrict__ tableV,
    _Float16* __restrict__ fcwT, unsigned* __restrict__ zbuf,
    unsigned* __restrict__ bar) {
  const int blk = blockIdx.x, tid = threadIdx.x;
  if (blk < 2048) {
    // tableV[v][C] = emb[v]·w_ih0[row(C)] + b_ih0[row] + b_hh0[row]
    const int C = blk * 2 + (tid >> 7);
    const int v = tid & 127;
    const int row =
        ((C >> 2) & 3) * 1024 + (C >> 5) * 8 + ((C >> 4) & 1) * 4 + (C & 3);
    float acc = b_ih0[row] + b_hh0[row];
    const float* er = emb + v * 512;
    const float* wr = w_ih0 + row * 512;
#pragma unroll 4
    for (int k = 0; k < 512; ++k) acc = fmaf(er[k], wr[k], acc);
    tableV[v * 4096 + C] = (_Float16)acc;
  } else if (blk < 2560) {
    const int idx = (blk - 2048) * 256 + tid;   // [0, 131072)
    const int v = idx & 127, k = idx >> 7;
    fcwT[k * 128 + v] = (_Float16)fc_w[v * 1024 + k];
  } else if (blk < 2592) {
    // zero hseq buffers 0 and 1 (step-0/1 initial h state): 131072 dwords
    const int idx = (blk - 2560) * 256 + tid;
#pragma unroll
    for (int q = 0; q < 16; ++q) zbuf[idx * 16 + q] = 0u;
  } else {
    for (int i = tid; i < 512; i += 256) bar[i] = 0u;
  }
}

// ------------------------------------------------------------ recurrent ----
__global__ __launch_bounds__(512, 1) void lstm_mfma(
    const int* __restrict__ x, const _Float16* __restrict__ tableV,
    const float* __restrict__ w_hh0, const float* __restrict__ w_ih1,
    const float* __restrict__ w_hh1, const float* __restrict__ b_ih1,
    const float* __restrict__ b_hh1, _Float16* __restrict__ hseq,
    unsigned* __restrict__ bar) {
  // [slot12][r4][rq8][col32] floats, col32 = (cb*16+colp)^((rq&1)<<4): 48 KB
  __shared__ __align__(16) float zs[12 * 4 * 8 * 32];

  const int tid = threadIdx.x, blk = blockIdx.x;
  const int w = tid >> 6, l = tid & 63;
  const int lane16 = l & 15, quad = l >> 4;
  // XCD-local cg grouping: all 8 writer-blocks of any 128-B h line share
  // blk&7 (== XCD under the %8 round-robin dispatch).
  const int xcd = blk & 7, bidx = blk >> 3;
  const int m = bidx >> 4, cg = xcd * 16 + (bidx & 15);

  // --- stage B-fragments into REGISTERS (once) ---
  // bh: w<4 -> w_hh0 (layer0); w>=4 -> w_hh1 (layer1 high-K).
  // bi: w<4 only -> w_ih1 (layer1 low-K = xin1 contribution).
  v8h bh0[8], bh1[8], bi0[8], bi1[8];
  {
    const int g = lane16 >> 2, j = lane16 & 3;
    const float* Wsrc = (w < 4) ? w_hh0 : w_hh1;
    const int kbase = (w < 4) ? w * 256 : w * 256 - 1024;
#pragma unroll
    for (int cb = 0; cb < 2; ++cb) {
      const int row = g * 1024 + cg * 8 + cb * 4 + j;
      const float* rp = Wsrc + row * 1024 + kbase + quad * 8;
#pragma unroll
      for (int kk = 0; kk < 8; ++kk) {
        const float4 f0 = *(const float4*)(rp + kk * 32);
        const float4 f1 = *(const float4*)(rp + kk * 32 + 4);
        v8h b;
        b[0] = (_Float16)f0.x; b[1] = (_Float16)f0.y;
        b[2] = (_Float16)f0.z; b[3] = (_Float16)f0.w;
        b[4] = (_Float16)f1.x; b[5] = (_Float16)f1.y;
        b[6] = (_Float16)f1.z; b[7] = (_Float16)f1.w;
        if (cb == 0) bh0[kk] = b; else bh1[kk] = b;
      }
    }
    if (w < 4) {
#pragma unroll
      for (int cb = 0; cb < 2; ++cb) {
        const int row = g * 1024 + cg * 8 + cb * 4 + j;
        const float* rp = w_ih1 + row * 1024 + w * 256 + quad * 8;
#pragma unroll
        for (int kk = 0; kk < 8; ++kk) {
          const float4 f0 = *(const float4*)(rp + kk * 32);
          const float4 f1 = *(const float4*)(rp + kk * 32 + 4);
          v8h b;
          b[0] = (_Float16)f0.x; b[1] = (_Float16)f0.y;
          b[2] = (_Float16)f0.z; b[3] = (_Float16)f0.w;
          b[4] = (_Float16)f1.x; b[5] = (_Float16)f1.y;
          b[6] = (_Float16)f1.z; b[7] = (_Float16)f1.w;
          if (cb == 0) bi0[kk] = b; else bi1[kk] = b;
        }
      }
    }
  }

  // --- elementwise-owner constants ---
  const int oj = l & 7, ojj = l & 3, ocb = (l >> 2) & 1;
  const int ob = (w & 3) * 8 + (l >> 3);
  const int obg = m * 32 + ob;
  // swizzle constants
  const int colp = (lane16 & 3) * 4 + (lane16 >> 2);      // j*4+g
  const int cswz = colp ^ ((quad & 1) << 4);              // write col, cb=0
  const int rr = ob & 3, rqo = ob >> 2;                   // owner row split
  const int rcol = (ocb * 16 + ojj * 4) ^ ((rqo & 1) << 4);  // owner read col

  v4f bias4 = {0.f, 0.f, 0.f, 0.f};
  if (w >= 4) {
#pragma unroll
    for (int g = 0; g < 4; ++g) {
      const int row = g * 1024 + cg * 8 + ocb * 4 + ojj;
      bias4[g] = b_ih1[row] + b_hh1[row];
    }
  }
  _Float16 tvh[4] = {0, 0, 0, 0};
  if (w < 4) {
    const int xv = x[obg * 512];
#pragma unroll
    for (int g = 0; g < 4; ++g)
      tvh[g] = tableV[xv * 4096 + cg * 32 + ocb * 16 + g * 4 + ojj];
  }

  float cst = 0.0f;
  const int gq = blk & 7;   // arrival word within this m-half

  for (int it = 0; it <= 512; ++it) {
    const _Float16* hr = hseq + (size_t)it * 131072;       // fresh buffers
    _Float16* hw = hseq + (size_t)(it + 1) * 131072;

    // p* = layer0 tiles (w<4) or layer1-hh tiles (w>=4); q* = layer1-xin1
    v4f p00 = {0, 0, 0, 0}, p01 = {0, 0, 0, 0};
    v4f p10 = {0, 0, 0, 0}, p11 = {0, 0, 0, 0};
    v4f q00 = {0, 0, 0, 0}, q01 = {0, 0, 0, 0};
    v4f q10 = {0, 0, 0, 0}, q11 = {0, 0, 0, 0};
    const bool ld = (w < 4) || (it >= 1);
    if (ld) {
      // A: rows m*32 + mt*16 + lane16, halfs w*256 + kk*32 + quad*8
      // PLAIN CACHED loads: buffer `it` is fresh for this XCD's L2 (or
      // holds only same-XCD write-through lines) -> always coherent.
      // R9: ONE asm block, 16 global_load_dwordx4 -> 16 early-clobber
      // v8h results (64 VGPR forced live), single vmcnt(0). All 16 loads
      // in flight = one memory latency instead of 4-8 windowed ones.
      const _Float16* a0p = hr + (m * 32 + lane16) * 2048 + w * 256 + quad * 8;
      const _Float16* a1p = a0p + 16 * 2048;
      v8h A0_0, A0_1, A0_2, A0_3, A0_4, A0_5, A0_6, A0_7;
      v8h A1_0, A1_1, A1_2, A1_3, A1_4, A1_5, A1_6, A1_7;
      asm volatile(
          "global_load_dwordx4 %[r0], %[pa], off\n\t"
          "global_load_dwordx4 %[r1], %[pa], off offset:64\n\t"
          "global_load_dwordx4 %[r2], %[pa], off offset:128\n\t"
          "global_load_dwordx4 %[r3], %[pa], off offset:192\n\t"
          "global_load_dwordx4 %[r4], %[pa], off offset:256\n\t"
          "global_load_dwordx4 %[r5], %[pa], off offset:320\n\t"
          "global_load_dwordx4 %[r6], %[pa], off offset:384\n\t"
          "global_load_dwordx4 %[r7], %[pa], off offset:448\n\t"
          "global_load_dwordx4 %[s0], %[pb], off\n\t"
          "global_load_dwordx4 %[s1], %[pb], off offset:64\n\t"
          "global_load_dwordx4 %[s2], %[pb], off offset:128\n\t"
          "global_load_dwordx4 %[s3], %[pb], off offset:192\n\t"
          "global_load_dwordx4 %[s4], %[pb], off offset:256\n\t"
          "global_load_dwordx4 %[s5], %[pb], off offset:320\n\t"
          "global_load_dwordx4 %[s6], %[pb], off offset:384\n\t"
          "global_load_dwordx4 %[s7], %[pb], off offset:448\n\t"
          "s_waitcnt vmcnt(0)"
          : [r0] "=&v"(A0_0), [r1] "=&v"(A0_1), [r2] "=&v"(A0_2),
            [r3] "=&v"(A0_3), [r4] "=&v"(A0_4), [r5] "=&v"(A0_5),
            [r6] "=&v"(A0_6), [r7] "=&v"(A0_7), [s0] "=&v"(A1_0),
            [s1] "=&v"(A1_1), [s2] "=&v"(A1_2), [s3] "=&v"(A1_3),
            [s4] "=&v"(A1_4), [s5] "=&v"(A1_5), [s6] "=&v"(A1_6),
            [s7] "=&v"(A1_7)
          : [pa] "v"(a0p), [pb] "v"(a1p)
          : "memory");
      // SROA resolves these array refs to the named regs (no copies)
      const v8h A0[8] = {A0_0, A0_1, A0_2, A0_3, A0_4, A0_5, A0_6, A0_7};
      const v8h A1[8] = {A1_0, A1_1, A1_2, A1_3, A1_4, A1_5, A1_6, A1_7};
      if (w < 4) {
        if (it < 512) {
#pragma unroll
          for (int kk = 0; kk < 8; ++kk) {
            p00 = __builtin_amdgcn_mfma_f32_16x16x32_f16(A0[kk], bh0[kk], p00, 0, 0, 0);
            p10 = __builtin_amdgcn_mfma_f32_16x16x32_f16(A0[kk], bh1[kk], p10, 0, 0, 0);
            p01 = __builtin_amdgcn_mfma_f32_16x16x32_f16(A1[kk], bh0[kk], p01, 0, 0, 0);
            p11 = __builtin_amdgcn_mfma_f32_16x16x32_f16(A1[kk], bh1[kk], p11, 0, 0, 0);
          }
        }
        if (it >= 1) {
#pragma unroll
          for (int kk = 0; kk < 8; ++kk) {
            q00 = __builtin_amdgcn_mfma_f32_16x16x32_f16(A0[kk], bi0[kk], q00, 0, 0, 0);
            q10 = __builtin_amdgcn_mfma_f32_16x16x32_f16(A0[kk], bi1[kk], q10, 0, 0, 0);
            q01 = __builtin_amdgcn_mfma_f32_16x16x32_f16(A1[kk], bi0[kk], q01, 0, 0, 0);
            q11 = __builtin_amdgcn_mfma_f32_16x16x32_f16(A1[kk], bi1[kk], q11, 0, 0, 0);
          }
        }
      } else {
#pragma unroll
        for (int kk = 0; kk < 8; ++kk) {
          p00 = __builtin_amdgcn_mfma_f32_16x16x32_f16(A0[kk], bh0[kk], p00, 0, 0, 0);
          p10 = __builtin_amdgcn_mfma_f32_16x16x32_f16(A0[kk], bh1[kk], p10, 0, 0, 0);
          p01 = __builtin_amdgcn_mfma_f32_16x16x32_f16(A1[kk], bh0[kk], p01, 0, 0, 0);
          p11 = __builtin_amdgcn_mfma_f32_16x16x32_f16(A1[kk], bh1[kk], p11, 0, 0, 0);
        }
      }
    }

    // C-tiles -> LDS, swizzled (R4 layout). Slots: w<4 -> p@w, q@w+4;
    // w>=4 -> p@w+4. Banks: 2-way max on writes.
    if (w < 4) {
#pragma unroll
      for (int r = 0; r < 4; ++r) {
        float* zpa = &zs[((w * 4 + r) * 8 + quad) * 32];
        zpa[cswz] = p00[r];
        zpa[128 + cswz] = p01[r];
        zpa[cswz ^ 16] = p10[r];
        zpa[128 + (cswz ^ 16)] = p11[r];
        float* zpb = &zs[(((w + 4) * 4 + r) * 8 + quad) * 32];
        zpb[cswz] = q00[r];
        zpb[128 + cswz] = q01[r];
        zpb[cswz ^ 16] = q10[r];
        zpb[128 + (cswz ^ 16)] = q11[r];
      }
    } else {
#pragma unroll
      for (int r = 0; r < 4; ++r) {
        float* zpb = &zs[(((w + 4) * 4 + r) * 8 + quad) * 32];
        zpb[cswz] = p00[r];
        zpb[128 + cswz] = p01[r];
        zpb[cswz ^ 16] = p10[r];
        zpb[128 + (cswz ^ 16)] = p11[r];
      }
    }
    __syncthreads();

    // owner reduction + cell update (vector b128 reads, gates contiguous)
    const bool do0 = (w < 4) && (it < 512);
    const bool do1 = (w >= 4) && (it >= 1);
    if (do0 || do1) {
      v4f z;
      if (do0) {
        z[0] = (float)tvh[0]; z[1] = (float)tvh[1];
        z[2] = (float)tvh[2]; z[3] = (float)tvh[3];
#pragma unroll
        for (int wv = 0; wv < 4; ++wv)
          z += *(const v4f*)&zs[((wv * 4 + rr) * 8 + rqo) * 32 + rcol];
      } else {
        z = bias4;
#pragma unroll
        for (int wv = 4; wv < 12; ++wv)
          z += *(const v4f*)&zs[((wv * 4 + rr) * 8 + rqo) * 32 + rcol];
      }
      const float ig = sigf(z[0]), fg = sigf(z[1]);
      const float gg = tanhfast(z[2]), og = sigf(z[3]);
      cst = fg * cst + ig * gg;
      const float hv = og * tanhfast(cst);

      // pack 8 unit-lanes (same b) -> two 8-B stores (lanes oj==0, oj==4)
      const unsigned hu =
          (unsigned)__builtin_bit_cast(unsigned short, (_Float16)hv);
      const unsigned p1 = (unsigned)__shfl_xor((int)hu, 1, 64);
      const unsigned lo = (oj & 1) ? ((p1 & 0xffffu) | (hu << 16))
                                   : ((hu & 0xffffu) | (p1 << 16));
      const unsigned p2 = (unsigned)__shfl_xor((int)lo, 2, 64);
      if ((oj & 3) == 0) {
        const u64t val = (u64t)lo | ((u64t)p2 << 32);
        if (do0) {
          __hip_atomic_store((u64t*)(hw + obg * 2048 + cg * 8 + oj), val,
                             __ATOMIC_RELAXED, __HIP_MEMORY_SCOPE_AGENT);
        } else {
          __hip_atomic_store((u64t*)(hw + obg * 2048 + 1024 + cg * 8 + oj),
                             val, __ATOMIC_RELAXED, __HIP_MEMORY_SCOPE_AGENT);
        }
      }
    }

    // prefetch next step's xin0 gather (tableV constant, L1-hot)
    if (w < 4 && it + 1 < 512) {
      const int xv = x[obg * 512 + it + 1];
#pragma unroll
      for (int g = 0; g < 4; ++g)
        tvh[g] = tableV[xv * 4096 + cg * 32 + ocb * 16 + g * 4 + ojj];
    }

    if (it < 512) {
      // ---- flat m-split barrier: one add, one poll stage, no leaders ----
      asm volatile("s_waitcnt vmcnt(0)" ::: "memory");  // h stores at L3
      __syncthreads();
      if (tid == 0) {
        atomicAdd(&bar[(m * 8 + gq) * 16], 1u);         // fire-and-forget
        const unsigned tgt = 16u * (unsigned)(it + 1);
        for (;;) {
          unsigned v[8];
#pragma unroll
          for (int g = 0; g < 8; ++g)
            v[g] = __hip_atomic_load(&bar[(m * 8 + g) * 16], __ATOMIC_RELAXED,
                                     __HIP_MEMORY_SCOPE_AGENT);
          unsigned mn = v[0];
#pragma unroll
          for (int g = 1; g < 8; ++g) mn = (v[g] < mn) ? v[g] : mn;
          if (mn >= tgt) break;
          __builtin_amdgcn_s_sleep(1);
        }
      }
      __syncthreads();
      // keep the fresh-buffer plain loads from being hoisted above release
      asm volatile("" ::: "memory");
    }
  }
}

// ---------------------------------------------------------------- FC ----
__global__ __launch_bounds__(256, 2) void fc_kernel(
    const _Float16* __restrict__ hseq, const _Float16* __restrict__ fcwT,
    const float* __restrict__ fc_b, float* __restrict__ out) {
  __shared__ float hl[16][1024];      // 64 KB
  const int tid = threadIdx.x;
  const int t = blockIdx.x >> 2, bs = blockIdx.x & 3;
  const int v = tid & 127, hh = tid >> 7;

  // h2[t][b][u] lives at hseq buffer t+2, row b, halfs 1024..2047
  const h2v* hp = (const h2v*)hseq;
  const size_t base = (size_t)(t + 2) * 65536 + 512;
  for (int idx = tid; idx < 8192; idx += 256) {
    const int bl = idx >> 9, kp = idx & 511;
    const h2v pr = hp[base + (size_t)((bs * 16 + bl)) * 1024 + kp];
    hl[bl][2 * kp] = (float)pr.x;
    hl[bl][2 * kp + 1] = (float)pr.y;
  }
  __syncthreads();

  float acc[8];
#pragma unroll
  for (int i = 0; i < 8; ++i) acc[i] = 0.0f;
  const int bl0 = hh * 8;
#pragma unroll 1
  for (int k4 = 0; k4 < 256; ++k4) {
    const int k = k4 * 4;
    const float w0 = (float)fcwT[(k + 0) * 128 + v];
    const float w1 = (float)fcwT[(k + 1) * 128 + v];
    const float w2 = (float)fcwT[(k + 2) * 128 + v];
    const float w3 = (float)fcwT[(k + 3) * 128 + v];
#pragma unroll
    for (int i = 0; i < 8; ++i) {
      const float4 hv = *(const float4*)&hl[bl0 + i][k];
      acc[i] += hv.x * w0 + hv.y * w1 + hv.z * w2 + hv.w * w3;
    }
  }
  const float bias = fc_b[v];
#pragma unroll
  for (int i = 0; i < 8; ++i) {
    const int bb = bs * 16 + bl0 + i;
    out[(bb * 512 + t) * 128 + v] = acc[i] + bias;
  }
}

// ------------------------------------------------------------- launch ----
extern "C" void kernel_launch(void* const* d_in, const int* in_sizes, int n_in,
                              void* d_out, int out_size, void* d_ws,
                              size_t ws_size, hipStream_t stream) {
  const int* x = (const int*)d_in[0];
  const float* emb = (const float*)d_in[1];
  const float* w_ih0 = (const float*)d_in[2];
  const float* w_hh0 = (const float*)d_in[3];
  const float* b_ih0 = (const float*)d_in[4];
  const float* b_hh0 = (const float*)d_in[5];
  const float* w_ih1 = (const float*)d_in[6];
  const float* w_hh1 = (const float*)d_in[7];
  const float* b_ih1 = (const float*)d_in[8];
  const float* b_hh1 = (const float*)d_in[9];
  const float* fc_w = (const float*)d_in[10];
  const float* fc_b = (const float*)d_in[11];
  float* out = (float*)d_out;

  char* ws = (char*)d_ws;
  _Float16* tableV = (_Float16*)(ws);
  _Float16* fcwT = (_Float16*)(ws + 1048576);
  unsigned* bar = (unsigned*)(ws + 1310720);
  _Float16* hseq = (_Float16*)(ws + 1376256);   // 514 x 262144 B
  unsigned* zb = (unsigned*)(ws + 1376256);     // zero buffers 0,1

  prep_kernel<<<2593, 256, 0, stream>>>(emb, w_ih0, b_ih0, b_hh0, fc_w,
                                        tableV, fcwT, zb, bar);

  const _Float16* tableVc = tableV;
  _Float16* hseqa = hseq;
  unsigned* bara = bar;
  void* args[] = {(void*)&x,     (void*)&tableVc, (void*)&w_hh0,
                  (void*)&w_ih1, (void*)&w_hh1,   (void*)&b_ih1,
                  (void*)&b_hh1, (void*)&hseqa,   (void*)&bara};
  hipLaunchCooperativeKernel(lstm_mfma, dim3(256), dim3(512), args, 0, stream);

  fc_kernel<<<2048, 256, 0, stream>>>(hseq, fcwT, fc_b, out);
}

// Round 10
// 3967.195 us; speedup vs baseline: 1.0720x; 1.0720x over previous
//
#include <hip/hip_runtime.h>

// Shapes: VOCAB=128, EMBED=512, HIDDEN=1024, B=64, T=512. Inputs fp32, x int32.
// ws layout (bytes):
//   tableV : [128 vocab][4096 C] fp16   @ 0         (1 MB)  xin0+bias
//   fcwT   : [1024 k][128 v] fp16       @ 1048576   (256 KB)
//   bar    : [512 words] u32            @ 1310720   (2 KB)  class counters
//   hseq   : [514 buf][64 b][2048 k]f16 @ 1376256   (128.5 MB) fresh h per step
//
// L0/L1 PIPELINE SPLIT (R10): layer0 is a self-contained recurrence
// (h1(t+1) = f(h1(t), x)); layer1 only CONSUMES h1. Previous designs
// serialized both layers' MFMA+reduce+stores inside one barrier span
// (R6 measured that span at ~7.3 us with instant polls). Now:
//   L0-blocks (blk 0..127):  2m x 64 cg2, 16 units, K=1024 (w_hh0).
//     Critical loop gated ONLY by cnt0 (own class). 32 MFMA/wave.
//   L1-blocks (blk 128..255): 2m x 64 cg2, 16 units, K=2048 (w_ih1+w_hh1).
//     Gated by cnt0 (h1) + cnt1 (h2, own class). Trails L0; its ~2 us
//     step cost is NOT on the recurrence critical path (throughput <
//     L0 step time, so it never becomes the bottleneck).
// Counters: cnt0[m][g] @ word (m*8+g)*16, cnt1[m][g] @ ((2+m)*8+g)*16,
// g=0..7; arrival = tid0 atomicAdd after per-lane vmcnt(0) drain + sync
// (8 blocks/word fan-in, below R5's failure threshold); consumer tid0
// polls min-of-8 (R2 pattern).
//
// FRESH-BUFFER h EXCHANGE (R1): step it reads buffer it, writes buffer
// it+1; no XCD (L2 or L1$) ever touched buffer it+1 before its poll
// passes -> plain cached dwordx4 loads are coherent. Stores agent-scope
// relaxed atomics (write-through at L3). Line-ownership: cg2 = xcd*8+idx
// ==> every 128-B h line is written only by ONE XCD (blk%8 round-robin;
// L1 blocks 128+q have (128+q)&7 == q&7, same mapping).
// buffer[t+2][b][1024+u] IS h2[t] -> FC reads hseq directly.
//
// SWIZZLED LDS REDUCTION (R4, generalized to 64-col tiles):
// zs[w8][r4][rq8][col64], col = (ct*16 + colp) ^ ((rq&1)<<4),
// colp = jj*4+g (lane16 = g*4+jj). Writes: 64 lanes spread exactly 2/bank
// (free). Owner reads: aligned v4f, 4 gates contiguous, at LDS BW floor.
// Every thread owns one cell: b = w*4+quad, uu = lane16.
// Transcendentals: __expf + division only (proven on this harness).

typedef _Float16 v8h __attribute__((ext_vector_type(8)));
typedef float v4f __attribute__((ext_vector_type(4)));
typedef _Float16 h2v __attribute__((ext_vector_type(2)));
typedef unsigned long long u64t;

__device__ __forceinline__ float sigf(float x) {
  return 1.0f / (1.0f + __expf(-x));
}
__device__ __forceinline__ float tanhfast(float x) {
  // tanh = 1 - 2/(e^{2x}+1); graceful at +-inf (__expf -> inf/0)
  return 1.0f - 2.0f / (1.0f + __expf(2.0f * x));
}

// ---------------------------------------------------------------- prep ----
__global__ __launch_bounds__(256) void prep_kernel(
    const float* __restrict__ emb, const float* __restrict__ w_ih0,
    const float* __restrict__ b_ih0, const float* __restrict__ b_hh0,
    const float* __restrict__ fc_w, _Float16* __restrict__ tableV,
    _Float16* __restrict__ fcwT, unsigned* __restrict__ zbuf,
    unsigned* __restrict__ bar) {
  const int blk = blockIdx.x, tid = threadIdx.x;
  if (blk < 2048) {
    // tableV[v][C] = emb[v]·w_ih0[row(C)] + b_ih0[row] + b_hh0[row]
    const int C = blk * 2 + (tid >> 7);
    const int v = tid & 127;
    const int row =
        ((C >> 2) & 3) * 1024 + (C >> 5) * 8 + ((C >> 4) & 1) * 4 + (C & 3);
    const float* er = emb + v * 512;
    const float* wr = w_ih0 + row * 512;
    float a0 = 0.f, a1 = 0.f, a2 = 0.f, a3 = 0.f;   // 4-way ILP (R10)
#pragma unroll 4
    for (int k = 0; k < 512; k += 4) {
      a0 = fmaf(er[k], wr[k], a0);
      a1 = fmaf(er[k + 1], wr[k + 1], a1);
      a2 = fmaf(er[k + 2], wr[k + 2], a2);
      a3 = fmaf(er[k + 3], wr[k + 3], a3);
    }
    tableV[v * 4096 + C] =
        (_Float16)(b_ih0[row] + b_hh0[row] + ((a0 + a1) + (a2 + a3)));
  } else if (blk < 2560) {
    const int idx = (blk - 2048) * 256 + tid;   // [0, 131072)
    const int v = idx & 127, k = idx >> 7;
    fcwT[k * 128 + v] = (_Float16)fc_w[v * 1024 + k];
  } else if (blk < 2592) {
    // zero hseq buffers 0 and 1 (step-0/1 initial h state): 131072 dwords
    const int idx = (blk - 2560) * 256 + tid;
#pragma unroll
    for (int q = 0; q < 16; ++q) zbuf[idx * 16 + q] = 0u;
  } else {
    for (int i = tid; i < 512; i += 256) bar[i] = 0u;
  }
}

// ------------------------------------------------------------ recurrent ----
__global__ __launch_bounds__(512, 1) void lstm_mfma(
    const int* __restrict__ x, const _Float16* __restrict__ tableV,
    const float* __restrict__ w_hh0, const float* __restrict__ w_ih1,
    const float* __restrict__ w_hh1, const float* __restrict__ b_ih1,
    const float* __restrict__ b_hh1, _Float16* __restrict__ hseq,
    unsigned* __restrict__ bar) {
  // [w8][r4][rq8][col64] floats = 64 KB
  __shared__ __align__(16) float zs[8 * 4 * 8 * 64];

  const int tid = threadIdx.x, blk = blockIdx.x;
  const bool isL1 = blk >= 128;
  const int sub = isL1 ? blk - 128 : blk;
  const int xcd = sub & 7, bidx = sub >> 3;        // xcd == blk&7 both classes
  const int m = bidx >> 3, cg2 = xcd * 8 + (bidx & 7);   // cg2 in 0..63
  const int w = tid >> 6, l = tid & 63;
  const int lane16 = l & 15, quad = l >> 4;
  const int g = lane16 >> 2, jj = lane16 & 3;
  const int colp = jj * 4 + g;                     // write col perm

  // --- owner constants (every thread owns one cell) ---
  const int b = w * 4 + quad;                      // batch row within m
  const int uu = lane16;                           // unit within block's 16
  const int bg = m * 32 + b;
  const int ubase = (isL1 ? 1024 : 0) + cg2 * 16;
  const int colo = ((uu >> 2) * 16 + (uu & 3) * 4) ^ ((w & 1) << 4);

  float cst = 0.0f;

  if (!isL1) {
    // =================== L0: the critical recurrence ===================
    // B-frags: w_hh0, wave w covers k in [w*128, +128) -> [ct][kk<4]
    v8h bf[4][4];
#pragma unroll
    for (int ct = 0; ct < 4; ++ct) {
      const int row = g * 1024 + cg2 * 16 + ct * 4 + jj;
      const float* rp = w_hh0 + row * 1024 + w * 128 + quad * 8;
#pragma unroll
      for (int kk = 0; kk < 4; ++kk) {
        const float4 f0 = *(const float4*)(rp + kk * 32);
        const float4 f1 = *(const float4*)(rp + kk * 32 + 4);
        v8h bb;
        bb[0] = (_Float16)f0.x; bb[1] = (_Float16)f0.y;
        bb[2] = (_Float16)f0.z; bb[3] = (_Float16)f0.w;
        bb[4] = (_Float16)f1.x; bb[5] = (_Float16)f1.y;
        bb[6] = (_Float16)f1.z; bb[7] = (_Float16)f1.w;
        bf[ct][kk] = bb;
      }
    }
    // xin0 gather constants
    const int Cbase = (cg2 * 2 + (uu >> 3)) * 32 + ((uu >> 2) & 1) * 16 + (uu & 3);
    _Float16 tvh[4];
    {
      const int xv = x[bg * 512];
#pragma unroll
      for (int gg = 0; gg < 4; ++gg)
        tvh[gg] = tableV[xv * 4096 + Cbase + gg * 4];
    }
    unsigned* arr = &bar[(m * 8 + xcd) * 16];
    const unsigned* pw = &bar[(m * 8) * 16];

    for (int it = 0; it < 512; ++it) {
      if (tid == 0 && it > 0) {
        const unsigned tgt = 8u * (unsigned)it;
        for (;;) {
          unsigned mn = 0xffffffffu;
#pragma unroll
          for (int gg = 0; gg < 8; ++gg) {
            const unsigned vv = __hip_atomic_load(
                pw + gg * 16, __ATOMIC_RELAXED, __HIP_MEMORY_SCOPE_AGENT);
            mn = vv < mn ? vv : mn;
          }
          if (mn >= tgt) break;
          __builtin_amdgcn_s_sleep(1);
        }
      }
      __syncthreads();
      asm volatile("" ::: "memory");
      const _Float16* hr = hseq + (size_t)it * 131072;
      _Float16* hw = hseq + (size_t)(it + 1) * 131072;

      // A: rows m*32+lane16 (+16), k = w*128 + kk*32 + quad*8
      const _Float16* a0p = hr + (m * 32 + lane16) * 2048 + w * 128 + quad * 8;
      const _Float16* a1p = a0p + 16 * 2048;
      v8h A0[4], A1[4];
#pragma unroll
      for (int kk = 0; kk < 4; ++kk) A0[kk] = *(const v8h*)(a0p + kk * 32);
#pragma unroll
      for (int kk = 0; kk < 4; ++kk) A1[kk] = *(const v8h*)(a1p + kk * 32);
      v4f ac0[4] = {{0, 0, 0, 0}, {0, 0, 0, 0}, {0, 0, 0, 0}, {0, 0, 0, 0}};
      v4f ac1[4] = {{0, 0, 0, 0}, {0, 0, 0, 0}, {0, 0, 0, 0}, {0, 0, 0, 0}};
#pragma unroll
      for (int kk = 0; kk < 4; ++kk)
#pragma unroll
        for (int ct = 0; ct < 4; ++ct) {
          ac0[ct] = __builtin_amdgcn_mfma_f32_16x16x32_f16(A0[kk], bf[ct][kk], ac0[ct], 0, 0, 0);
          ac1[ct] = __builtin_amdgcn_mfma_f32_16x16x32_f16(A1[kk], bf[ct][kk], ac1[ct], 0, 0, 0);
        }

      // C-tiles -> LDS (swizzled; writes exactly 2 lanes/bank = free)
#pragma unroll
      for (int r = 0; r < 4; ++r)
#pragma unroll
        for (int ct = 0; ct < 4; ++ct) {
          const int col = (ct * 16 + colp) ^ ((quad & 1) << 4);
          zs[((w * 4 + r) * 8 + quad) * 64 + col] = ac0[ct][r];
          zs[((w * 4 + r) * 8 + 4 + quad) * 64 + col] = ac1[ct][r];
        }
      __syncthreads();

      // owner reduction (8 slots) + cell update
      v4f z;
      z[0] = (float)tvh[0]; z[1] = (float)tvh[1];
      z[2] = (float)tvh[2]; z[3] = (float)tvh[3];
#pragma unroll
      for (int wv = 0; wv < 8; ++wv)
        z += *(const v4f*)&zs[((wv * 4 + quad) * 8 + w) * 64 + colo];
      const float ig = sigf(z[0]), fg = sigf(z[1]);
      const float gg2 = tanhfast(z[2]), og = sigf(z[3]);
      cst = fg * cst + ig * gg2;
      const float hv = og * tanhfast(cst);

      // pack 4 unit-lanes -> one 8-B store per 4 units
      const unsigned hu =
          (unsigned)__builtin_bit_cast(unsigned short, (_Float16)hv);
      const unsigned p1 = (unsigned)__shfl_xor((int)hu, 1, 64);
      const unsigned lo = (l & 1) ? ((p1 & 0xffffu) | (hu << 16))
                                  : ((hu & 0xffffu) | (p1 << 16));
      const unsigned p2 = (unsigned)__shfl_xor((int)lo, 2, 64);
      if ((l & 3) == 0) {
        const u64t val = (u64t)lo | ((u64t)p2 << 32);
        __hip_atomic_store((u64t*)(hw + bg * 2048 + ubase + (l & 15)), val,
                           __ATOMIC_RELAXED, __HIP_MEMORY_SCOPE_AGENT);
      }
      // prefetch next xin0 gather (tableV L2-hot)
      if (it + 1 < 512) {
        const int xv = x[bg * 512 + it + 1];
#pragma unroll
        for (int gg = 0; gg < 4; ++gg)
          tvh[gg] = tableV[xv * 4096 + Cbase + gg * 4];
      }
      asm volatile("s_waitcnt vmcnt(0)" ::: "memory");
      __syncthreads();
      if (tid == 0) atomicAdd(arr, 1u);
    }
  } else {
    // =================== L1: trailing consumer pipeline ===================
    // B-frags: w<4 -> w_ih1 k=[w*256,+256); w>=4 -> w_hh1 k-1024
    v8h bf[4][8];
    {
      const float* Wsrc = (w < 4) ? w_ih1 : w_hh1;
      const int kbase = (w < 4) ? w * 256 : w * 256 - 1024;
#pragma unroll
      for (int ct = 0; ct < 4; ++ct) {
        const int row = g * 1024 + cg2 * 16 + ct * 4 + jj;
        const float* rp = Wsrc + row * 1024 + kbase + quad * 8;
#pragma unroll
        for (int kk = 0; kk < 8; ++kk) {
          const float4 f0 = *(const float4*)(rp + kk * 32);
          const float4 f1 = *(const float4*)(rp + kk * 32 + 4);
          v8h bb;
          bb[0] = (_Float16)f0.x; bb[1] = (_Float16)f0.y;
          bb[2] = (_Float16)f0.z; bb[3] = (_Float16)f0.w;
          bb[4] = (_Float16)f1.x; bb[5] = (_Float16)f1.y;
          bb[6] = (_Float16)f1.z; bb[7] = (_Float16)f1.w;
          bf[ct][kk] = bb;
        }
      }
    }
    v4f bias4;
#pragma unroll
    for (int gg = 0; gg < 4; ++gg) {
      const int row = gg * 1024 + cg2 * 16 + uu;
      bias4[gg] = b_ih1[row] + b_hh1[row];
    }
    unsigned* arr = &bar[((2 + m) * 8 + xcd) * 16];
    const unsigned* pw0 = &bar[(m * 8) * 16];
    const unsigned* pw1 = &bar[((2 + m) * 8) * 16];

    for (int it = 1; it <= 512; ++it) {
      if (tid == 0) {
        const unsigned t0 = 8u * (unsigned)it;
        const unsigned t1 = 8u * (unsigned)(it - 1);
        for (;;) {
          unsigned mn0 = 0xffffffffu, mn1 = 0xffffffffu;
#pragma unroll
          for (int gg = 0; gg < 8; ++gg) {
            const unsigned v0 = __hip_atomic_load(
                pw0 + gg * 16, __ATOMIC_RELAXED, __HIP_MEMORY_SCOPE_AGENT);
            const unsigned v1 = __hip_atomic_load(
                pw1 + gg * 16, __ATOMIC_RELAXED, __HIP_MEMORY_SCOPE_AGENT);
            mn0 = v0 < mn0 ? v0 : mn0;
            mn1 = v1 < mn1 ? v1 : mn1;
          }
          if (mn0 >= t0 && mn1 >= t1) break;
          __builtin_amdgcn_s_sleep(1);
        }
      }
      __syncthreads();
      asm volatile("" ::: "memory");
      const _Float16* hr = hseq + (size_t)it * 131072;
      _Float16* hw = hseq + (size_t)(it + 1) * 131072;

      const _Float16* a0p = hr + (m * 32 + lane16) * 2048 + w * 256 + quad * 8;
      const _Float16* a1p = a0p + 16 * 2048;
      v8h A0[8], A1[8];
#pragma unroll
      for (int kk = 0; kk < 8; ++kk) A0[kk] = *(const v8h*)(a0p + kk * 32);
#pragma unroll
      for (int kk = 0; kk < 8; ++kk) A1[kk] = *(const v8h*)(a1p + kk * 32);
      v4f ac0[4] = {{0, 0, 0, 0}, {0, 0, 0, 0}, {0, 0, 0, 0}, {0, 0, 0, 0}};
      v4f ac1[4] = {{0, 0, 0, 0}, {0, 0, 0, 0}, {0, 0, 0, 0}, {0, 0, 0, 0}};
#pragma unroll
      for (int kk = 0; kk < 8; ++kk)
#pragma unroll
        for (int ct = 0; ct < 4; ++ct) {
          ac0[ct] = __builtin_amdgcn_mfma_f32_16x16x32_f16(A0[kk], bf[ct][kk], ac0[ct], 0, 0, 0);
          ac1[ct] = __builtin_amdgcn_mfma_f32_16x16x32_f16(A1[kk], bf[ct][kk], ac1[ct], 0, 0, 0);
        }

#pragma unroll
      for (int r = 0; r < 4; ++r)
#pragma unroll
        for (int ct = 0; ct < 4; ++ct) {
          const int col = (ct * 16 + colp) ^ ((quad & 1) << 4);
          zs[((w * 4 + r) * 8 + quad) * 64 + col] = ac0[ct][r];
          zs[((w * 4 + r) * 8 + 4 + quad) * 64 + col] = ac1[ct][r];
        }
      __syncthreads();

      v4f z = bias4;
#pragma unroll
      for (int wv = 0; wv < 8; ++wv)
        z += *(const v4f*)&zs[((wv * 4 + quad) * 8 + w) * 64 + colo];
      const float ig = sigf(z[0]), fg = sigf(z[1]);
      const float gg2 = tanhfast(z[2]), og = sigf(z[3]);
      cst = fg * cst + ig * gg2;
      const float hv = og * tanhfast(cst);

      const unsigned hu =
          (unsigned)__builtin_bit_cast(unsigned short, (_Float16)hv);
      const unsigned p1 = (unsigned)__shfl_xor((int)hu, 1, 64);
      const unsigned lo = (l & 1) ? ((p1 & 0xffffu) | (hu << 16))
                                  : ((hu & 0xffffu) | (p1 << 16));
      const unsigned p2 = (unsigned)__shfl_xor((int)lo, 2, 64);
      if ((l & 3) == 0) {
        const u64t val = (u64t)lo | ((u64t)p2 << 32);
        __hip_atomic_store((u64t*)(hw + bg * 2048 + ubase + (l & 15)), val,
                           __ATOMIC_RELAXED, __HIP_MEMORY_SCOPE_AGENT);
      }
      asm volatile("s_waitcnt vmcnt(0)" ::: "memory");
      __syncthreads();
      if (tid == 0) atomicAdd(arr, 1u);
    }
  }
}

// ---------------------------------------------------------------- FC ----
__global__ __launch_bounds__(256, 2) void fc_kernel(
    const _Float16* __restrict__ hseq, const _Float16* __restrict__ fcwT,
    const float* __restrict__ fc_b, float* __restrict__ out) {
  __shared__ float hl[16][1024];      // 64 KB
  const int tid = threadIdx.x;
  const int t = blockIdx.x >> 2, bs = blockIdx.x & 3;
  const int v = tid & 127, hh = tid >> 7;

  // h2[t][b][u] lives at hseq buffer t+2, row b, halfs 1024..2047
  const h2v* hp = (const h2v*)hseq;
  const size_t base = (size_t)(t + 2) * 65536 + 512;
  for (int idx = tid; idx < 8192; idx += 256) {
    const int bl = idx >> 9, kp = idx & 511;
    const h2v pr = hp[base + (size_t)((bs * 16 + bl)) * 1024 + kp];
    hl[bl][2 * kp] = (float)pr.x;
    hl[bl][2 * kp + 1] = (float)pr.y;
  }
  __syncthreads();

  float acc[8];
#pragma unroll
  for (int i = 0; i < 8; ++i) acc[i] = 0.0f;
  const int bl0 = hh * 8;
#pragma unroll 1
  for (int k4 = 0; k4 < 256; ++k4) {
    const int k = k4 * 4;
    const float w0 = (float)fcwT[(k + 0) * 128 + v];
    const float w1 = (float)fcwT[(k + 1) * 128 + v];
    const float w2 = (float)fcwT[(k + 2) * 128 + v];
    const float w3 = (float)fcwT[(k + 3) * 128 + v];
#pragma unroll
    for (int i = 0; i < 8; ++i) {
      const float4 hv = *(const float4*)&hl[bl0 + i][k];
      acc[i] += hv.x * w0 + hv.y * w1 + hv.z * w2 + hv.w * w3;
    }
  }
  const float bias = fc_b[v];
#pragma unroll
  for (int i = 0; i < 8; ++i) {
    const int bb = bs * 16 + bl0 + i;
    out[(bb * 512 + t) * 128 + v] = acc[i] + bias;
  }
}

// ------------------------------------------------------------- launch ----
extern "C" void kernel_launch(void* const* d_in, const int* in_sizes, int n_in,
                              void* d_out, int out_size, void* d_ws,
                              size_t ws_size, hipStream_t stream) {
  const int* x = (const int*)d_in[0];
  const float* emb = (const float*)d_in[1];
  const float* w_ih0 = (const float*)d_in[2];
  const float* w_hh0 = (const float*)d_in[3];
  const float* b_ih0 = (const float*)d_in[4];
  const float* b_hh0 = (const float*)d_in[5];
  const float* w_ih1 = (const float*)d_in[6];
  const float* w_hh1 = (const float*)d_in[7];
  const float* b_ih1 = (const float*)d_in[8];
  const float* b_hh1 = (const float*)d_in[9];
  const float* fc_w = (const float*)d_in[10];
  const float* fc_b = (const float*)d_in[11];
  float* out = (float*)d_out;

  char* ws = (char*)d_ws;
  _Float16* tableV = (_Float16*)(ws);
  _Float16* fcwT = (_Float16*)(ws + 1048576);
  unsigned* bar = (unsigned*)(ws + 1310720);
  _Float16* hseq = (_Float16*)(ws + 1376256);   // 514 x 262144 B
  unsigned* zb = (unsigned*)(ws + 1376256);     // zero buffers 0,1

  prep_kernel<<<2593, 256, 0, stream>>>(emb, w_ih0, b_ih0, b_hh0, fc_w,
                                        tableV, fcwT, zb, bar);

  const _Float16* tableVc = tableV;
  _Float16* hseqa = hseq;
  unsigned* bara = bar;
  void* args[] = {(void*)&x,     (void*)&tableVc, (void*)&w_hh0,
                  (void*)&w_ih1, (void*)&w_hh1,   (void*)&b_ih1,
                  (void*)&b_hh1, (void*)&hseqa,   (void*)&bara};
  hipLaunchCooperativeKernel(lstm_mfma, dim3(256), dim3(512), args, 0, stream);

  fc_kernel<<<2048, 256, 0, stream>>>(hseq, fcwT, fc_b, out);
}